// Round 4
// baseline (6934.274 us; speedup 1.0000x reference)
//
#include <hip/hip_runtime.h>
#include <math.h>

#define SEQ   512
#define BATCH 64
#define HID   512
#define NROW  1536                     // 3 gates * HID rows
#define XROW_FLOATS ((size_t)SEQ * NROW * BATCH)   // 201.3 MB
#define HBUF_QWORDS (2 * BATCH * HID)              // double-buffered tagged h, u64 [parity][b][j]
#define SBH ((size_t)SEQ * BATCH * HID)

__device__ __forceinline__ float sigf(float x) {
    return 1.f / (1.f + __expf(-x));
}
__device__ __forceinline__ float tanh_fast(float x) {
    float ax = fabsf(x);
    float e = __expf(-2.f * ax);
    float r = (1.f - e) / (1.f + e);
    return copysignf(r, x);
}
// butterfly add via DPP (VALU pipe, not LDS); ctrl is a template constant.
template <int CTRL>
__device__ __forceinline__ float dpp_add(float v) {
    int x = __builtin_amdgcn_update_dpp(0, __builtin_bit_cast(int, v),
                                        CTRL, 0xf, 0xf, true);
    return v + __builtin_bit_cast(float, x);
}

// ---------------- Phase 1: xrow[t][gate*512+j][b] = dot(x[t,b,:], Wx[g][j,:]) ----------------
// v2: w LDS staging DELETED. Weight reads are wave-uniform -> compiler emits
// s_load (scalar pipe) + v_fma with SGPR operand; the LDS pipe only carries the
// per-lane x reads. LDS drops 99.3 KB -> 66.6 KB, so 2 wgs/CU are resident
// (grid 512 = 2 per CU) -> 2 waves/SIMD of latency hiding instead of 1.
__global__ __launch_bounds__(256, 2) void xproj_kernel(
    const float* __restrict__ x, const float* __restrict__ Wxi,
    const float* __restrict__ Wxc, const float* __restrict__ Wxo,
    float* __restrict__ xrow)
{
    extern __shared__ float lds[];
    float* xT = lds;                              // [256][65] = 66560 B
    const int tid = threadIdx.x, lane = tid & 63, wv = tid >> 6;
    const int t = blockIdx.x;

    for (int kh = 0; kh < 2; ++kh) {
        __syncthreads();
        for (int b = wv; b < 64; b += 4) {
            const float* xp = x + ((size_t)t * 64 + b) * 512 + kh * 256;
            #pragma unroll
            for (int q = 0; q < 4; ++q) {
                int k = lane + q * 64;
                xT[k * 65 + b] = xp[k];
            }
        }
        __syncthreads();

        for (int m = 0; m < 48; ++m) {
            const int R0 = (wv + 4 * m) * 8;
            // 8 wave-uniform row base pointers -> w loads become scalar loads
            const float* wr[8];
            #pragma unroll
            for (int r = 0; r < 8; ++r) {
                const int R = R0 + r, g = R >> 9, j = R & 511;
                const float* wsrc = (g == 0) ? Wxi : ((g == 1) ? Wxc : Wxo);
                wr[r] = wsrc + (size_t)j * 512 + kh * 256;
            }
            float acc[8] = {0.f, 0.f, 0.f, 0.f, 0.f, 0.f, 0.f, 0.f};
            #pragma unroll 2
            for (int c = 0; c < 64; ++c) {
                const float x0 = xT[(4 * c + 0) * 65 + lane];
                const float x1 = xT[(4 * c + 1) * 65 + lane];
                const float x2 = xT[(4 * c + 2) * 65 + lane];
                const float x3 = xT[(4 * c + 3) * 65 + lane];
                #pragma unroll
                for (int r = 0; r < 8; ++r) {
                    const float4 w4 = *(const float4*)(wr[r] + 4 * c);  // uniform -> s_load_dwordx4
                    acc[r] += x0 * w4.x + x1 * w4.y + x2 * w4.z + x3 * w4.w;
                }
            }
            #pragma unroll
            for (int r = 0; r < 8; ++r) {
                const size_t o = ((size_t)t * NROW + R0 + r) * 64 + lane;
                if (kh) xrow[o] += acc[r];
                else    xrow[o]  = acc[r];
            }
        }
    }
}

// ---------------- Phase 2: batch-partitioned persistent scan ----------------
// 256 wgs x 384 thr; group gid = blockIdx%8 owns 8 batches, member m = blockIdx/8
// owns 16 j x 3 gates = 48 rows. Data-is-the-flag tagged-u64 h exchange.
// v3:
//  * recurrent weights live in REGISTERS (w4r[16][4], 64 VGPR/thread) -- the
//    106 KB wlds and its 16 conflicted ds_read_b128/thread/step are gone.
//  * HPAD 12 -> 10: h reads become ds_read_b64 at stride 40 B, gcd(10,32)=2
//    -> 2-way bank aliasing, which is free (m136). Conflicts ~vanish.
//  * poll retry reordered: reload FIRST, then s_sleep while loads are in
//    flight (was: sleep, then serial reload round-trip).
#define HPAD 10                        // h LDS row stride (2-way = free, 8B-aligned)
#define H_FLOATS (512 * HPAD)          // 5120
__global__ __launch_bounds__(384) void scan_kernel(
    const float* __restrict__ xrow,
    const float* __restrict__ Whi, const float* __restrict__ Whc, const float* __restrict__ Who,
    const float* __restrict__ bi, const float* __restrict__ bc, const float* __restrict__ bo,
    unsigned long long* __restrict__ hbuf, float* __restrict__ out)
{
    extern __shared__ float lds[];
    float* hlds = lds;                         // [512 k][10] b in 0..7
    float* gbuf = lds + H_FLOATS;              // [48 rho][8 b]
    float* biasL = gbuf + 384;                 // [48]

    const int tid = threadIdx.x, lane = tid & 63;
    const int gid = blockIdx.x & 7;            // batch group
    const int m   = blockIdx.x >> 3;           // j-slice member 0..31
    const int rg  = tid >> 5, ks = tid & 31;   // GEMM coords (rg in 0..11)

    // ---- one-time: recurrent weights into registers ----
    // w4r[i][r] = W_row(m*16 + (rg&3)*4 + r)[ks + 32*i], gate g = rg>>2.
    // Lane ks varies fastest -> each (r,i) is one coalesced 128B load.
    float w4r[16][4];
    {
        const int g  = rg >> 2;
        const int jb = m * 16 + (rg & 3) * 4;
        const float* wsrc = (g == 0) ? Whi : ((g == 1) ? Whc : Who);
        #pragma unroll
        for (int r = 0; r < 4; ++r) {
            const float* wp = wsrc + (size_t)(jb + r) * 512 + ks;
            #pragma unroll
            for (int i = 0; i < 16; ++i) w4r[i][r] = wp[32 * i];
        }
    }
    if (tid < 48) {
        const int g = tid >> 4, jloc = tid & 15;
        const float* bb = (g == 0) ? bi : ((g == 1) ? bc : bo);
        biasL[tid] = bb[m * 16 + jloc];
    }

    // epilogue identity (tid < 128): j-fastest for coalesced global stores
    const int ejl = tid & 15, eb = tid >> 4;
    const int jg  = m * 16 + ejl;              // global j
    const int bg  = gid * 8 + eb;              // global batch
    float creg = 0.f;

    // own slice of h_0 = 0 directly into LDS (staging always skips own k-range)
    if (tid < 128) hlds[jg * HPAD + eb] = 0.f;
    __syncthreads();

    for (int t = 0; t < SEQ; ++t) {
        // ---- prefetch this step's xrow terms (independent of h, overlaps staging) ----
        float xr0 = 0.f, xr1 = 0.f, xr2 = 0.f;
        if (tid < 128) {
            const size_t base = ((size_t)t * NROW + jg) * 64 + bg;
            xr0 = xrow[base];
            xr1 = xrow[base + (size_t)512 * 64];
            xr2 = xrow[base + (size_t)1024 * 64];
        }

        // ---- stage h_t: tagged loads, poll-in-place; own k-range comes via LDS ----
        {
            const unsigned long long* hsrc =
                hbuf + (size_t)(t & 1) * (BATCH * HID) + (size_t)gid * 8 * 512;
            const unsigned tgt = (unsigned)t;
            unsigned long long hv[11];
            unsigned pend = 0;
            #pragma unroll
            for (int q = 0; q < 11; ++q) {
                const int i = tid + q * 384;            // i = b*512 + k, b<8
                if (i < 4096 && ((i & 511) >> 4) != m) {
                    hv[q] = __hip_atomic_load(hsrc + i, __ATOMIC_RELAXED,
                                              __HIP_MEMORY_SCOPE_AGENT);
                    pend |= 1u << q;
                }
            }
            while (pend) {
                unsigned np = 0;
                #pragma unroll
                for (int q = 0; q < 11; ++q) {
                    if ((pend >> q) & 1) {
                        const int i = tid + q * 384;
                        if ((unsigned)(hv[q] >> 32) >= tgt) {
                            hlds[(i & 511) * HPAD + (i >> 9)] =
                                __builtin_bit_cast(float, (unsigned)hv[q]);
                        } else np |= 1u << q;
                    }
                }
                if (np) {
                    // reload FIRST (loads in flight), sleep to cover the latency
                    #pragma unroll
                    for (int q = 0; q < 11; ++q)
                        if ((np >> q) & 1)
                            hv[q] = __hip_atomic_load(hsrc + (tid + q * 384),
                                                      __ATOMIC_RELAXED,
                                                      __HIP_MEMORY_SCOPE_AGENT);
                    __builtin_amdgcn_s_sleep(1);
                }
                pend = np;
            }
        }
        __syncthreads();

        // ---- GEMM: acc[r][b] = sum_k w4r[i][r] * h[k][b], k = ks+32i ----
        float acc[4][8];
        #pragma unroll
        for (int r = 0; r < 4; ++r)
            #pragma unroll
            for (int b = 0; b < 8; ++b) acc[r][b] = 0.f;

        {
            const float* hb = hlds + ks * HPAD;
            #pragma unroll
            for (int i = 0; i < 16; ++i) {
                float hv2[8];
                *(float2*)&hv2[0] = *(const float2*)(hb + i * (32 * HPAD) + 0);
                *(float2*)&hv2[2] = *(const float2*)(hb + i * (32 * HPAD) + 2);
                *(float2*)&hv2[4] = *(const float2*)(hb + i * (32 * HPAD) + 4);
                *(float2*)&hv2[6] = *(const float2*)(hb + i * (32 * HPAD) + 6);
                #pragma unroll
                for (int r = 0; r < 4; ++r)
                    #pragma unroll
                    for (int b = 0; b < 8; ++b)
                        acc[r][b] += w4r[i][r] * hv2[b];
            }
            // ---- reduce over ks on the VALU pipe ----
            #pragma unroll
            for (int r = 0; r < 4; ++r)
                #pragma unroll
                for (int b = 0; b < 8; ++b) {
                    float v = acc[r][b];
                    v = dpp_add<0x121>(v);  // row_ror:1
                    v = dpp_add<0x122>(v);  // row_ror:2
                    v = dpp_add<0x124>(v);  // row_ror:4
                    v = dpp_add<0x128>(v);  // row_ror:8
                    v = dpp_add<0x142>(v);  // row_bcast15 -> lanes 16..31/48..63
                    acc[r][b] = v;
                }
            if (lane == 16 || lane == 48) {
                #pragma unroll
                for (int r = 0; r < 4; ++r) {
                    float* gp = gbuf + (rg * 4 + r) * 8;
                    *(float4*)gp       = make_float4(acc[r][0], acc[r][1], acc[r][2], acc[r][3]);
                    *(float4*)(gp + 4) = make_float4(acc[r][4], acc[r][5], acc[r][6], acc[r][7]);
                }
            }
        }
        __syncthreads();

        // ---- elementwise update (tid < 128): thread = (eb, ejl); publish tagged h ----
        if (tid < 128) {
            const float pi = xr0 + biasL[ejl]      + gbuf[(0 * 16 + ejl) * 8 + eb];
            const float pc = xr1 + biasL[16 + ejl] + gbuf[(1 * 16 + ejl) * 8 + eb];
            const float po = xr2 + biasL[32 + ejl] + gbuf[(2 * 16 + ejl) * 8 + eb];
            const float it = sigf(pi);
            const float ch = tanh_fast(pc);
            const float ot = sigf(po);
            creg = (1.f - it) * creg + it * ch;       // coupled forget gate
            const float hn = ot * tanh_fast(creg);
            const unsigned long long pv =
                ((unsigned long long)(unsigned)(t + 1) << 32) |
                (unsigned long long)__builtin_bit_cast(unsigned, hn);
            // publish first: it is the cross-wg critical path
            __hip_atomic_store(hbuf + (size_t)((t + 1) & 1) * (BATCH * HID)
                                    + (size_t)bg * 512 + jg,
                               pv, __ATOMIC_RELAXED, __HIP_MEMORY_SCOPE_AGENT);
            hlds[jg * HPAD + eb] = hn;                // self-bypass for next step
            out[((size_t)t * 64 + bg) * 512 + jg] = hn;
            if (t == SEQ - 1) {
                out[SBH + (size_t)bg * 512 + jg] = hn;             // h_T
                out[SBH + 32768 + (size_t)bg * 512 + jg] = creg;   // c_T
            }
        }
        // no drain, no flag, no trailing barrier: next iteration's staging only
        // touches hlds entries outside every concurrent reader's range, and the
        // tagged store IS the publication.
    }
}

extern "C" void kernel_launch(void* const* d_in, const int* in_sizes, int n_in,
                              void* d_out, int out_size, void* d_ws, size_t ws_size,
                              hipStream_t stream)
{
    const float* x   = (const float*)d_in[0];
    const float* Wxi = (const float*)d_in[1];
    const float* Whi = (const float*)d_in[2];
    const float* bi  = (const float*)d_in[3];
    const float* Wxc = (const float*)d_in[4];
    const float* Whc = (const float*)d_in[5];
    const float* bc  = (const float*)d_in[6];
    const float* Wxo = (const float*)d_in[7];
    const float* Who = (const float*)d_in[8];
    const float* bo  = (const float*)d_in[9];
    float* out = (float*)d_out;
    char* ws = (char*)d_ws;

    float*              xrow = (float*)ws;
    unsigned long long* hbuf = (unsigned long long*)(ws + XROW_FLOATS * 4);

    // zero tagged h double-buffer: (tag=0, h=0.0f) == h_0, every call
    (void)hipMemsetAsync(hbuf, 0, (size_t)HBUF_QWORDS * 8, stream);

    // xproj LDS: xT only = 256*65*4 = 66560 B  (2 wgs/CU resident)
    hipLaunchKernelGGL(xproj_kernel, dim3(512), dim3(256), 66560, stream,
                       x, Wxi, Wxc, Wxo, xrow);
    // scan LDS: h 5120 + gbuf 384 + bias 48 = 5552 floats = 22208 B
    hipLaunchKernelGGL(scan_kernel, dim3(256), dim3(384), 22208, stream,
                       xrow, Whi, Whc, Who, bi, bc, bo, hbuf, out);
}

// Round 5
// 6211.174 us; speedup vs baseline: 1.1164x; 1.1164x over previous
//
#include <hip/hip_runtime.h>
#include <math.h>

#define SEQ   512
#define BATCH 64
#define HID   512
#define NROW  1536                     // 3 gates * HID rows
#define XROW_FLOATS ((size_t)SEQ * NROW * BATCH)   // 201.3 MB
#define HBUF_QWORDS (2 * BATCH * HID)              // double-buffered tagged h, u64 [parity][b][j]
#define SBH ((size_t)SEQ * BATCH * HID)

__device__ __forceinline__ float sigf(float x) {
    return 1.f / (1.f + __expf(-x));
}
__device__ __forceinline__ float tanh_fast(float x) {
    float ax = fabsf(x);
    float e = __expf(-2.f * ax);
    float r = (1.f - e) / (1.f + e);
    return copysignf(r, x);
}
// butterfly add via DPP (VALU pipe, not LDS); ctrl is a template constant.
template <int CTRL>
__device__ __forceinline__ float dpp_add(float v) {
    int x = __builtin_amdgcn_update_dpp(0, __builtin_bit_cast(int, v),
                                        CTRL, 0xf, 0xf, true);
    return v + __builtin_bit_cast(float, x);
}

// ---------------- Phase 1: xrow[t][gate*512+j][b] = dot(x[t,b,:], Wx[g][j,:]) ----------------
// REVERTED to the r2 version (LDS-staged weights): the "uniform pointer ->
// s_load" rewrite did NOT scalarize (compiler emitted per-lane broadcast
// global loads, VMEM-latency-bound at 2 waves/SIMD) and cost ~+770 us.
__global__ __launch_bounds__(256) void xproj_kernel(
    const float* __restrict__ x, const float* __restrict__ Wxi,
    const float* __restrict__ Wxc, const float* __restrict__ Wxo,
    float* __restrict__ xrow)
{
    extern __shared__ float lds[];
    float* xT = lds;                              // [256][65]
    const int tid = threadIdx.x, lane = tid & 63, wv = tid >> 6;
    float* wl = lds + 256 * 65 + wv * (8 * 256);  // per-wave [8 rows][256 k]
    const int t = blockIdx.x;

    for (int kh = 0; kh < 2; ++kh) {
        __syncthreads();
        for (int b = wv; b < 64; b += 4) {
            const float* xp = x + ((size_t)t * 64 + b) * 512 + kh * 256;
            #pragma unroll
            for (int q = 0; q < 4; ++q) {
                int k = lane + q * 64;
                xT[k * 65 + b] = xp[k];
            }
        }
        __syncthreads();

        for (int m = 0; m < 48; ++m) {
            const int Bk = wv + 4 * m;
            const int R0 = Bk * 8;
            #pragma unroll
            for (int r = 0; r < 8; ++r) {
                const int R = R0 + r, g = R >> 9, j = R & 511;
                const float* wsrc = (g == 0) ? Wxi : ((g == 1) ? Wxc : Wxo);
                const float4 w4 = *(const float4*)(wsrc + (size_t)j * 512 + kh * 256 + lane * 4);
                *(float4*)(wl + r * 256 + lane * 4) = w4;
            }
            float acc[8] = {0.f, 0.f, 0.f, 0.f, 0.f, 0.f, 0.f, 0.f};
            #pragma unroll 2
            for (int c = 0; c < 64; ++c) {
                const float x0 = xT[(4 * c + 0) * 65 + lane];
                const float x1 = xT[(4 * c + 1) * 65 + lane];
                const float x2 = xT[(4 * c + 2) * 65 + lane];
                const float x3 = xT[(4 * c + 3) * 65 + lane];
                #pragma unroll
                for (int r = 0; r < 8; ++r) {
                    const float4 w4 = *(const float4*)(wl + r * 256 + c * 4);
                    acc[r] += x0 * w4.x + x1 * w4.y + x2 * w4.z + x3 * w4.w;
                }
            }
            #pragma unroll
            for (int r = 0; r < 8; ++r) {
                const size_t o = ((size_t)t * NROW + R0 + r) * 64 + lane;
                if (kh) xrow[o] += acc[r];
                else    xrow[o]  = acc[r];
            }
        }
    }
}

// ---------------- Phase 2: batch-partitioned persistent scan ----------------
// 256 wgs x 384 thr; group gid = blockIdx%8 owns 8 batches, member m = blockIdx/8
// owns 16 j x 3 gates = 48 rows. Data-is-the-flag tagged-u64 h exchange.
// v5: identical body to v3/v4 (functionally verified), with the r4 perf bug
// fixed: __launch_bounds__(384, 1). r4's bare (384) let the compiler cap at
// 128 VGPR -> ~25 regs spilled to scratch in the step loop (WRITE_SIZE
// 197 -> 673 MB, VALUBusy 32 -> 21%). With min-waves/EU = 1 the allocator can
// take ~160-190 VGPR; 6 waves/CU still fit (256-VGPR occupancy step = 8/CU).
//  * recurrent weights in REGISTERS (w4r[16][4]) -- no w LDS reads at all.
//  * HPAD 10: h reads are ds_read_b64, 2-way bank aliasing = free (m136).
//  * poll retry: reload FIRST, then s_sleep while loads are in flight.
#define HPAD 10                        // h LDS row stride (2-way = free, 8B-aligned)
#define H_FLOATS (512 * HPAD)          // 5120
__global__ __launch_bounds__(384, 1) void scan_kernel(
    const float* __restrict__ xrow,
    const float* __restrict__ Whi, const float* __restrict__ Whc, const float* __restrict__ Who,
    const float* __restrict__ bi, const float* __restrict__ bc, const float* __restrict__ bo,
    unsigned long long* __restrict__ hbuf, float* __restrict__ out)
{
    extern __shared__ float lds[];
    float* hlds = lds;                         // [512 k][10] b in 0..7
    float* gbuf = lds + H_FLOATS;              // [48 rho][8 b]
    float* biasL = gbuf + 384;                 // [48]

    const int tid = threadIdx.x, lane = tid & 63;
    const int gid = blockIdx.x & 7;            // batch group
    const int m   = blockIdx.x >> 3;           // j-slice member 0..31
    const int rg  = tid >> 5, ks = tid & 31;   // GEMM coords (rg in 0..11)

    // ---- one-time: recurrent weights into registers ----
    // w4r[i][r] = W_row(m*16 + (rg&3)*4 + r)[ks + 32*i], gate g = rg>>2.
    // Lane ks varies fastest -> each (r,i) is one coalesced 128B load.
    float w4r[16][4];
    {
        const int g  = rg >> 2;
        const int jb = m * 16 + (rg & 3) * 4;
        const float* wsrc = (g == 0) ? Whi : ((g == 1) ? Whc : Who);
        #pragma unroll
        for (int r = 0; r < 4; ++r) {
            const float* wp = wsrc + (size_t)(jb + r) * 512 + ks;
            #pragma unroll
            for (int i = 0; i < 16; ++i) w4r[i][r] = wp[32 * i];
        }
    }
    if (tid < 48) {
        const int g = tid >> 4, jloc = tid & 15;
        const float* bb = (g == 0) ? bi : ((g == 1) ? bc : bo);
        biasL[tid] = bb[m * 16 + jloc];
    }

    // epilogue identity (tid < 128): j-fastest for coalesced global stores
    const int ejl = tid & 15, eb = tid >> 4;
    const int jg  = m * 16 + ejl;              // global j
    const int bg  = gid * 8 + eb;              // global batch
    float creg = 0.f;

    // own slice of h_0 = 0 directly into LDS (staging always skips own k-range)
    if (tid < 128) hlds[jg * HPAD + eb] = 0.f;
    __syncthreads();

    for (int t = 0; t < SEQ; ++t) {
        // ---- prefetch this step's xrow terms (independent of h, overlaps staging) ----
        float xr0 = 0.f, xr1 = 0.f, xr2 = 0.f;
        if (tid < 128) {
            const size_t base = ((size_t)t * NROW + jg) * 64 + bg;
            xr0 = xrow[base];
            xr1 = xrow[base + (size_t)512 * 64];
            xr2 = xrow[base + (size_t)1024 * 64];
        }

        // ---- stage h_t: tagged loads, poll-in-place; own k-range comes via LDS ----
        {
            const unsigned long long* hsrc =
                hbuf + (size_t)(t & 1) * (BATCH * HID) + (size_t)gid * 8 * 512;
            const unsigned tgt = (unsigned)t;
            unsigned long long hv[11];
            unsigned pend = 0;
            #pragma unroll
            for (int q = 0; q < 11; ++q) {
                const int i = tid + q * 384;            // i = b*512 + k, b<8
                if (i < 4096 && ((i & 511) >> 4) != m) {
                    hv[q] = __hip_atomic_load(hsrc + i, __ATOMIC_RELAXED,
                                              __HIP_MEMORY_SCOPE_AGENT);
                    pend |= 1u << q;
                }
            }
            while (pend) {
                unsigned np = 0;
                #pragma unroll
                for (int q = 0; q < 11; ++q) {
                    if ((pend >> q) & 1) {
                        const int i = tid + q * 384;
                        if ((unsigned)(hv[q] >> 32) >= tgt) {
                            hlds[(i & 511) * HPAD + (i >> 9)] =
                                __builtin_bit_cast(float, (unsigned)hv[q]);
                        } else np |= 1u << q;
                    }
                }
                if (np) {
                    // reload FIRST (loads in flight), sleep to cover the latency
                    #pragma unroll
                    for (int q = 0; q < 11; ++q)
                        if ((np >> q) & 1)
                            hv[q] = __hip_atomic_load(hsrc + (tid + q * 384),
                                                      __ATOMIC_RELAXED,
                                                      __HIP_MEMORY_SCOPE_AGENT);
                    __builtin_amdgcn_s_sleep(1);
                }
                pend = np;
            }
        }
        __syncthreads();

        // ---- GEMM: acc[r][b] = sum_k w4r[i][r] * h[k][b], k = ks+32i ----
        float acc[4][8];
        #pragma unroll
        for (int r = 0; r < 4; ++r)
            #pragma unroll
            for (int b = 0; b < 8; ++b) acc[r][b] = 0.f;

        {
            const float* hb = hlds + ks * HPAD;
            #pragma unroll
            for (int i = 0; i < 16; ++i) {
                float hv2[8];
                *(float2*)&hv2[0] = *(const float2*)(hb + i * (32 * HPAD) + 0);
                *(float2*)&hv2[2] = *(const float2*)(hb + i * (32 * HPAD) + 2);
                *(float2*)&hv2[4] = *(const float2*)(hb + i * (32 * HPAD) + 4);
                *(float2*)&hv2[6] = *(const float2*)(hb + i * (32 * HPAD) + 6);
                #pragma unroll
                for (int r = 0; r < 4; ++r)
                    #pragma unroll
                    for (int b = 0; b < 8; ++b)
                        acc[r][b] += w4r[i][r] * hv2[b];
            }
            // ---- reduce over ks on the VALU pipe ----
            #pragma unroll
            for (int r = 0; r < 4; ++r)
                #pragma unroll
                for (int b = 0; b < 8; ++b) {
                    float v = acc[r][b];
                    v = dpp_add<0x121>(v);  // row_ror:1
                    v = dpp_add<0x122>(v);  // row_ror:2
                    v = dpp_add<0x124>(v);  // row_ror:4
                    v = dpp_add<0x128>(v);  // row_ror:8
                    v = dpp_add<0x142>(v);  // row_bcast15 -> lanes 16..31/48..63
                    acc[r][b] = v;
                }
            if (lane == 16 || lane == 48) {
                #pragma unroll
                for (int r = 0; r < 4; ++r) {
                    float* gp = gbuf + (rg * 4 + r) * 8;
                    *(float4*)gp       = make_float4(acc[r][0], acc[r][1], acc[r][2], acc[r][3]);
                    *(float4*)(gp + 4) = make_float4(acc[r][4], acc[r][5], acc[r][6], acc[r][7]);
                }
            }
        }
        __syncthreads();

        // ---- elementwise update (tid < 128): thread = (eb, ejl); publish tagged h ----
        if (tid < 128) {
            const float pi = xr0 + biasL[ejl]      + gbuf[(0 * 16 + ejl) * 8 + eb];
            const float pc = xr1 + biasL[16 + ejl] + gbuf[(1 * 16 + ejl) * 8 + eb];
            const float po = xr2 + biasL[32 + ejl] + gbuf[(2 * 16 + ejl) * 8 + eb];
            const float it = sigf(pi);
            const float ch = tanh_fast(pc);
            const float ot = sigf(po);
            creg = (1.f - it) * creg + it * ch;       // coupled forget gate
            const float hn = ot * tanh_fast(creg);
            const unsigned long long pv =
                ((unsigned long long)(unsigned)(t + 1) << 32) |
                (unsigned long long)__builtin_bit_cast(unsigned, hn);
            // publish first: it is the cross-wg critical path
            __hip_atomic_store(hbuf + (size_t)((t + 1) & 1) * (BATCH * HID)
                                    + (size_t)bg * 512 + jg,
                               pv, __ATOMIC_RELAXED, __HIP_MEMORY_SCOPE_AGENT);
            hlds[jg * HPAD + eb] = hn;                // self-bypass for next step
            out[((size_t)t * 64 + bg) * 512 + jg] = hn;
            if (t == SEQ - 1) {
                out[SBH + (size_t)bg * 512 + jg] = hn;             // h_T
                out[SBH + 32768 + (size_t)bg * 512 + jg] = creg;   // c_T
            }
        }
        // no drain, no flag, no trailing barrier: next iteration's staging only
        // touches hlds entries outside every concurrent reader's range, and the
        // tagged store IS the publication.
    }
}

extern "C" void kernel_launch(void* const* d_in, const int* in_sizes, int n_in,
                              void* d_out, int out_size, void* d_ws, size_t ws_size,
                              hipStream_t stream)
{
    const float* x   = (const float*)d_in[0];
    const float* Wxi = (const float*)d_in[1];
    const float* Whi = (const float*)d_in[2];
    const float* bi  = (const float*)d_in[3];
    const float* Wxc = (const float*)d_in[4];
    const float* Whc = (const float*)d_in[5];
    const float* bc  = (const float*)d_in[6];
    const float* Wxo = (const float*)d_in[7];
    const float* Who = (const float*)d_in[8];
    const float* bo  = (const float*)d_in[9];
    float* out = (float*)d_out;
    char* ws = (char*)d_ws;

    float*              xrow = (float*)ws;
    unsigned long long* hbuf = (unsigned long long*)(ws + XROW_FLOATS * 4);

    // zero tagged h double-buffer: (tag=0, h=0.0f) == h_0, every call
    (void)hipMemsetAsync(hbuf, 0, (size_t)HBUF_QWORDS * 8, stream);

    // xproj LDS: xT 256*65 + wl 4*8*256 = 24832 floats = 99328 B (r2 version)
    hipLaunchKernelGGL(xproj_kernel, dim3(512), dim3(256), 99328, stream,
                       x, Wxi, Wxc, Wxo, xrow);
    // scan LDS: h 5120 + gbuf 384 + bias 48 = 5552 floats = 22208 B
    hipLaunchKernelGGL(scan_kernel, dim3(256), dim3(384), 22208, stream,
                       xrow, Whi, Whc, Who, bi, bc, bo, hbuf, out);
}

// Round 6
// 4855.859 us; speedup vs baseline: 1.4280x; 1.2791x over previous
//
#include <hip/hip_runtime.h>
#include <math.h>

#define SEQ   512
#define BATCH 64
#define HID   512
#define NROW  1536                     // 3 gates * HID rows
#define XROW_FLOATS ((size_t)SEQ * NROW * BATCH)   // 201.3 MB
#define HBUF_QWORDS (2 * BATCH * HID)              // double-buffered tagged h, u64 [parity][b][j]
#define SBH ((size_t)SEQ * BATCH * HID)

__device__ __forceinline__ float sigf(float x) {
    return 1.f / (1.f + __expf(-x));
}
__device__ __forceinline__ float tanh_fast(float x) {
    float ax = fabsf(x);
    float e = __expf(-2.f * ax);
    float r = (1.f - e) / (1.f + e);
    return copysignf(r, x);
}
// butterfly add via DPP (VALU pipe, not LDS); ctrl is a template constant.
template <int CTRL>
__device__ __forceinline__ float dpp_add(float v) {
    int x = __builtin_amdgcn_update_dpp(0, __builtin_bit_cast(int, v),
                                        CTRL, 0xf, 0xf, true);
    return v + __builtin_bit_cast(float, x);
}

// ---------------- Phase 1: xrow[t][gate*512+j][b] = dot(x[t,b,:], Wx[g][j,:]) ----------------
// r2 version (LDS-staged weights) — measured ~2030 us; known good.
__global__ __launch_bounds__(256) void xproj_kernel(
    const float* __restrict__ x, const float* __restrict__ Wxi,
    const float* __restrict__ Wxc, const float* __restrict__ Wxo,
    float* __restrict__ xrow)
{
    extern __shared__ float lds[];
    float* xT = lds;                              // [256][65]
    const int tid = threadIdx.x, lane = tid & 63, wv = tid >> 6;
    float* wl = lds + 256 * 65 + wv * (8 * 256);  // per-wave [8 rows][256 k]
    const int t = blockIdx.x;

    for (int kh = 0; kh < 2; ++kh) {
        __syncthreads();
        for (int b = wv; b < 64; b += 4) {
            const float* xp = x + ((size_t)t * 64 + b) * 512 + kh * 256;
            #pragma unroll
            for (int q = 0; q < 4; ++q) {
                int k = lane + q * 64;
                xT[k * 65 + b] = xp[k];
            }
        }
        __syncthreads();

        for (int m = 0; m < 48; ++m) {
            const int Bk = wv + 4 * m;
            const int R0 = Bk * 8;
            #pragma unroll
            for (int r = 0; r < 8; ++r) {
                const int R = R0 + r, g = R >> 9, j = R & 511;
                const float* wsrc = (g == 0) ? Wxi : ((g == 1) ? Wxc : Wxo);
                const float4 w4 = *(const float4*)(wsrc + (size_t)j * 512 + kh * 256 + lane * 4);
                *(float4*)(wl + r * 256 + lane * 4) = w4;
            }
            float acc[8] = {0.f, 0.f, 0.f, 0.f, 0.f, 0.f, 0.f, 0.f};
            #pragma unroll 2
            for (int c = 0; c < 64; ++c) {
                const float x0 = xT[(4 * c + 0) * 65 + lane];
                const float x1 = xT[(4 * c + 1) * 65 + lane];
                const float x2 = xT[(4 * c + 2) * 65 + lane];
                const float x3 = xT[(4 * c + 3) * 65 + lane];
                #pragma unroll
                for (int r = 0; r < 8; ++r) {
                    const float4 w4 = *(const float4*)(wl + r * 256 + c * 4);
                    acc[r] += x0 * w4.x + x1 * w4.y + x2 * w4.z + x3 * w4.w;
                }
            }
            #pragma unroll
            for (int r = 0; r < 8; ++r) {
                const size_t o = ((size_t)t * NROW + R0 + r) * 64 + lane;
                if (kh) xrow[o] += acc[r];
                else    xrow[o]  = acc[r];
            }
        }
    }
}

// ---------------- Phase 2: batch-partitioned persistent scan ----------------
// 256 wgs x 512 thr; group gid = blockIdx%8 owns 8 batches, member m = blockIdx/8
// owns 16 j x 3 gates = 48 rows. Data-is-the-flag tagged-u64 h exchange.
// v6: 512 threads (8 waves) to fit the live set under the 128-VGPR allocator
// target WITHOUT spill (r4/r5 spilled ~2 dwords/thread/step: WRITE_SIZE
// 197 -> 673 MB, scratch L2-resident so FETCH unchanged -- the signature).
//   per-thread: w3r[16][3] = 48 VGPR (was 64), acc[3][8] = 24 (was 32),
//   staging exactly 8 qwords (4096 = 8*512, no tail; k = tid, b = q).
//   Peak live ~100-115 < 128.  __launch_bounds__(512,2) -> cap 256, margin.
#define HPAD 10                        // h LDS row stride (2-way = free, 8B-aligned)
#define H_FLOATS (512 * HPAD)          // 5120
__global__ __launch_bounds__(512, 2) void scan_kernel(
    const float* __restrict__ xrow,
    const float* __restrict__ Whi, const float* __restrict__ Whc, const float* __restrict__ Who,
    const float* __restrict__ bi, const float* __restrict__ bc, const float* __restrict__ bo,
    unsigned long long* __restrict__ hbuf, float* __restrict__ out)
{
    extern __shared__ float lds[];
    float* hlds = lds;                         // [512 k][10] b in 0..7
    float* gbuf = lds + H_FLOATS;              // [48 rho][8 b]
    float* biasL = gbuf + 384;                 // [48]

    const int tid = threadIdx.x, lane = tid & 63;
    const int gid = blockIdx.x & 7;            // batch group
    const int m   = blockIdx.x >> 3;           // j-slice member 0..31
    const int rg  = tid >> 5, ks = tid & 31;   // GEMM coords (rg in 0..15)

    // ---- one-time: recurrent weights into registers ----
    // w3r[i][r] = W_row(rho = rg*3 + r)[ks + 32*i]; rho in 0..47, g = rho>>4.
    // Lane ks varies fastest -> each (r,i) is one coalesced 128B load.
    float w3r[16][3];
    #pragma unroll
    for (int r = 0; r < 3; ++r) {
        const int rho = rg * 3 + r;
        const int g = rho >> 4, jloc = rho & 15;
        const float* wsrc = (g == 0) ? Whi : ((g == 1) ? Whc : Who);
        const float* wp = wsrc + (size_t)(m * 16 + jloc) * 512 + ks;
        #pragma unroll
        for (int i = 0; i < 16; ++i) w3r[i][r] = wp[32 * i];
    }
    if (tid < 48) {
        const int g = tid >> 4, jloc = tid & 15;
        const float* bb = (g == 0) ? bi : ((g == 1) ? bc : bo);
        biasL[tid] = bb[m * 16 + jloc];
    }

    // epilogue identity (tid < 128): j-fastest for coalesced global stores
    const int ejl = tid & 15, eb = tid >> 4;
    const int jg  = m * 16 + ejl;              // global j
    const int bg  = gid * 8 + eb;              // global batch
    float creg = 0.f;

    // own slice of h_0 = 0 directly into LDS (staging always skips own k-range)
    if (tid < 128) hlds[jg * HPAD + eb] = 0.f;
    __syncthreads();

    // staging identity: k = tid, b = q (exactly 8 qwords, no tail)
    const bool own_k = ((tid >> 4) == m);      // k in our own j-slice

    for (int t = 0; t < SEQ; ++t) {
        // ---- prefetch this step's xrow terms (independent of h, overlaps staging) ----
        float xr0 = 0.f, xr1 = 0.f, xr2 = 0.f;
        if (tid < 128) {
            const size_t base = ((size_t)t * NROW + jg) * 64 + bg;
            xr0 = xrow[base];
            xr1 = xrow[base + (size_t)512 * 64];
            xr2 = xrow[base + (size_t)1024 * 64];
        }

        // ---- stage h_t: tagged loads, poll-in-place; own k-range comes via LDS ----
        if (!own_k) {
            const unsigned long long* hsrc =
                hbuf + (size_t)(t & 1) * (BATCH * HID) + (size_t)gid * 8 * 512 + tid;
            const unsigned tgt = (unsigned)t;
            unsigned long long hv[8];
            #pragma unroll
            for (int q = 0; q < 8; ++q)
                hv[q] = __hip_atomic_load(hsrc + (size_t)q * 512, __ATOMIC_RELAXED,
                                          __HIP_MEMORY_SCOPE_AGENT);
            unsigned pend = 0xffu;
            while (pend) {
                unsigned np = 0;
                #pragma unroll
                for (int q = 0; q < 8; ++q) {
                    if ((pend >> q) & 1) {
                        if ((unsigned)(hv[q] >> 32) >= tgt) {
                            hlds[tid * HPAD + q] =
                                __builtin_bit_cast(float, (unsigned)hv[q]);
                        } else np |= 1u << q;
                    }
                }
                if (np) {
                    // reload FIRST (loads in flight), sleep to cover the latency
                    #pragma unroll
                    for (int q = 0; q < 8; ++q)
                        if ((np >> q) & 1)
                            hv[q] = __hip_atomic_load(hsrc + (size_t)q * 512,
                                                      __ATOMIC_RELAXED,
                                                      __HIP_MEMORY_SCOPE_AGENT);
                    __builtin_amdgcn_s_sleep(1);
                }
                pend = np;
            }
        }
        __syncthreads();

        // ---- GEMM: acc[r][b] = sum_k w3r[i][r] * h[k][b], k = ks+32i ----
        float acc[3][8];
        #pragma unroll
        for (int r = 0; r < 3; ++r)
            #pragma unroll
            for (int b = 0; b < 8; ++b) acc[r][b] = 0.f;

        {
            const float* hb = hlds + ks * HPAD;
            #pragma unroll
            for (int i = 0; i < 16; ++i) {
                float hv2[8];
                *(float2*)&hv2[0] = *(const float2*)(hb + i * (32 * HPAD) + 0);
                *(float2*)&hv2[2] = *(const float2*)(hb + i * (32 * HPAD) + 2);
                *(float2*)&hv2[4] = *(const float2*)(hb + i * (32 * HPAD) + 4);
                *(float2*)&hv2[6] = *(const float2*)(hb + i * (32 * HPAD) + 6);
                #pragma unroll
                for (int r = 0; r < 3; ++r)
                    #pragma unroll
                    for (int b = 0; b < 8; ++b)
                        acc[r][b] += w3r[i][r] * hv2[b];
            }
            // ---- reduce over ks on the VALU pipe ----
            #pragma unroll
            for (int r = 0; r < 3; ++r)
                #pragma unroll
                for (int b = 0; b < 8; ++b) {
                    float v = acc[r][b];
                    v = dpp_add<0x121>(v);  // row_ror:1
                    v = dpp_add<0x122>(v);  // row_ror:2
                    v = dpp_add<0x124>(v);  // row_ror:4
                    v = dpp_add<0x128>(v);  // row_ror:8
                    v = dpp_add<0x142>(v);  // row_bcast15 -> lanes 16..31/48..63
                    acc[r][b] = v;
                }
            if (lane == 16 || lane == 48) {
                #pragma unroll
                for (int r = 0; r < 3; ++r) {
                    float* gp = gbuf + (rg * 3 + r) * 8;
                    *(float4*)gp       = make_float4(acc[r][0], acc[r][1], acc[r][2], acc[r][3]);
                    *(float4*)(gp + 4) = make_float4(acc[r][4], acc[r][5], acc[r][6], acc[r][7]);
                }
            }
        }
        __syncthreads();

        // ---- elementwise update (tid < 128): thread = (eb, ejl); publish tagged h ----
        if (tid < 128) {
            const float pi = xr0 + biasL[ejl]      + gbuf[(0 * 16 + ejl) * 8 + eb];
            const float pc = xr1 + biasL[16 + ejl] + gbuf[(1 * 16 + ejl) * 8 + eb];
            const float po = xr2 + biasL[32 + ejl] + gbuf[(2 * 16 + ejl) * 8 + eb];
            const float it = sigf(pi);
            const float ch = tanh_fast(pc);
            const float ot = sigf(po);
            creg = (1.f - it) * creg + it * ch;       // coupled forget gate
            const float hn = ot * tanh_fast(creg);
            const unsigned long long pv =
                ((unsigned long long)(unsigned)(t + 1) << 32) |
                (unsigned long long)__builtin_bit_cast(unsigned, hn);
            // publish first: it is the cross-wg critical path
            __hip_atomic_store(hbuf + (size_t)((t + 1) & 1) * (BATCH * HID)
                                    + (size_t)bg * 512 + jg,
                               pv, __ATOMIC_RELAXED, __HIP_MEMORY_SCOPE_AGENT);
            hlds[jg * HPAD + eb] = hn;                // self-bypass for next step
            out[((size_t)t * 64 + bg) * 512 + jg] = hn;
            if (t == SEQ - 1) {
                out[SBH + (size_t)bg * 512 + jg] = hn;             // h_T
                out[SBH + 32768 + (size_t)bg * 512 + jg] = creg;   // c_T
            }
        }
        // no drain, no flag, no trailing barrier: next iteration's staging only
        // touches hlds entries outside every concurrent reader's range, and the
        // tagged store IS the publication.
    }
}

extern "C" void kernel_launch(void* const* d_in, const int* in_sizes, int n_in,
                              void* d_out, int out_size, void* d_ws, size_t ws_size,
                              hipStream_t stream)
{
    const float* x   = (const float*)d_in[0];
    const float* Wxi = (const float*)d_in[1];
    const float* Whi = (const float*)d_in[2];
    const float* bi  = (const float*)d_in[3];
    const float* Wxc = (const float*)d_in[4];
    const float* Whc = (const float*)d_in[5];
    const float* bc  = (const float*)d_in[6];
    const float* Wxo = (const float*)d_in[7];
    const float* Who = (const float*)d_in[8];
    const float* bo  = (const float*)d_in[9];
    float* out = (float*)d_out;
    char* ws = (char*)d_ws;

    float*              xrow = (float*)ws;
    unsigned long long* hbuf = (unsigned long long*)(ws + XROW_FLOATS * 4);

    // zero tagged h double-buffer: (tag=0, h=0.0f) == h_0, every call
    (void)hipMemsetAsync(hbuf, 0, (size_t)HBUF_QWORDS * 8, stream);

    // xproj LDS: xT 256*65 + wl 4*8*256 = 24832 floats = 99328 B (r2 version)
    hipLaunchKernelGGL(xproj_kernel, dim3(512), dim3(256), 99328, stream,
                       x, Wxi, Wxc, Wxo, xrow);
    // scan LDS: h 5120 + gbuf 384 + bias 48 = 5552 floats = 22208 B
    hipLaunchKernelGGL(scan_kernel, dim3(256), dim3(512), 22208, stream,
                       xrow, Whi, Whc, Who, bi, bc, bo, hbuf, out);
}

// Round 7
// 4797.969 us; speedup vs baseline: 1.4453x; 1.0121x over previous
//
#include <hip/hip_runtime.h>
#include <math.h>

#define SEQ   512
#define BATCH 64
#define HID   512
#define NROW  1536                     // 3 gates * HID rows
#define XROW_FLOATS ((size_t)SEQ * NROW * BATCH)   // 201.3 MB
#define HBUF_QWORDS (2 * BATCH * HID)              // double-buffered tagged h, u64 [parity][b][j]
#define SBH ((size_t)SEQ * BATCH * HID)

__device__ __forceinline__ float sigf(float x) {
    return 1.f / (1.f + __expf(-x));
}
__device__ __forceinline__ float tanh_fast(float x) {
    float ax = fabsf(x);
    float e = __expf(-2.f * ax);
    float r = (1.f - e) / (1.f + e);
    return copysignf(r, x);
}
// butterfly add via DPP (VALU pipe, not LDS); ctrl is a template constant.
template <int CTRL>
__device__ __forceinline__ float dpp_add(float v) {
    int x = __builtin_amdgcn_update_dpp(0, __builtin_bit_cast(int, v),
                                        CTRL, 0xf, 0xf, true);
    return v + __builtin_bit_cast(float, x);
}

// ---------------- Phase 1: xrow[t][gate*512+j][b] = dot(x[t,b,:], Wx[g][j,:]) ----------------
// v3: pure register-tiled GEMM, ZERO LDS. The r2 LDS version was LDS-issue
// bound: ~12 LDS insts per 64 VALU cycles per wave, 4 waves sharing one LDS
// pipe -> ~4x oversubscribed, 16% of the 328-us FLOP floor. Here each thread
// owns an 8-row x 4-batch tile (acc = 32 VGPR); per 4-k step: 8 w float4 + 4 x
// float4 from global (w shared by 16 lanes, x by 4 -> L1/L2 broadcast; W is
// L2-resident at 3 MB, x[t] = 128 KB). FMA:load = 128:12. 0 LDS -> 2 wgs/CU.
// Row-block math: mm*128 + wv*32 + rq*8 covers 0..1535 exactly once; gate
// boundaries (512) are multiples of 128, so each 8-row group is single-gate.
__global__ __launch_bounds__(256) void xproj_kernel(
    const float* __restrict__ x, const float* __restrict__ Wxi,
    const float* __restrict__ Wxc, const float* __restrict__ Wxo,
    float* __restrict__ xrow)
{
    const int tid = threadIdx.x, lane = tid & 63, wv = tid >> 6;
    const int t = blockIdx.x;
    const int bq = lane & 15;          // batch quad: b = 4*bq .. 4*bq+3
    const int rq = lane >> 4;          // row sub-block 0..3
    const float* xb = x + ((size_t)t * 64 + 4 * bq) * 512;

    for (int mm = 0; mm < 12; ++mm) {
        const int R0 = mm * 128 + wv * 32 + rq * 8;   // 8 rows, single gate
        const int g = R0 >> 9, j0 = R0 & 511;
        const float* wsrc = (g == 0) ? Wxi : ((g == 1) ? Wxc : Wxo);
        const float* wp = wsrc + (size_t)j0 * 512;

        float acc[8][4];
        #pragma unroll
        for (int r = 0; r < 8; ++r)
            #pragma unroll
            for (int j = 0; j < 4; ++j) acc[r][j] = 0.f;

        for (int k4 = 0; k4 < 128; ++k4) {
            float4 xv[4];
            #pragma unroll
            for (int j = 0; j < 4; ++j)
                xv[j] = *(const float4*)(xb + j * 512 + k4 * 4);
            #pragma unroll
            for (int r = 0; r < 8; ++r) {
                const float4 w4 = *(const float4*)(wp + (size_t)r * 512 + k4 * 4);
                #pragma unroll
                for (int j = 0; j < 4; ++j)
                    acc[r][j] += w4.x * xv[j].x + w4.y * xv[j].y
                               + w4.z * xv[j].z + w4.w * xv[j].w;
            }
        }
        #pragma unroll
        for (int r = 0; r < 8; ++r)
            *(float4*)(xrow + ((size_t)t * NROW + R0 + r) * 64 + 4 * bq) =
                make_float4(acc[r][0], acc[r][1], acc[r][2], acc[r][3]);
    }
}

// ---------------- Phase 2: batch-partitioned persistent scan ----------------
// FROZEN at r6 (verified: VGPR 96, no spill, 2800 us).
// 256 wgs x 512 thr; group gid = blockIdx%8 owns 8 batches, member m = blockIdx/8
// owns 16 j x 3 gates = 48 rows. Data-is-the-flag tagged-u64 h exchange.
#define HPAD 10                        // h LDS row stride (2-way = free, 8B-aligned)
#define H_FLOATS (512 * HPAD)          // 5120
__global__ __launch_bounds__(512, 2) void scan_kernel(
    const float* __restrict__ xrow,
    const float* __restrict__ Whi, const float* __restrict__ Whc, const float* __restrict__ Who,
    const float* __restrict__ bi, const float* __restrict__ bc, const float* __restrict__ bo,
    unsigned long long* __restrict__ hbuf, float* __restrict__ out)
{
    extern __shared__ float lds[];
    float* hlds = lds;                         // [512 k][10] b in 0..7
    float* gbuf = lds + H_FLOATS;              // [48 rho][8 b]
    float* biasL = gbuf + 384;                 // [48]

    const int tid = threadIdx.x, lane = tid & 63;
    const int gid = blockIdx.x & 7;            // batch group
    const int m   = blockIdx.x >> 3;           // j-slice member 0..31
    const int rg  = tid >> 5, ks = tid & 31;   // GEMM coords (rg in 0..15)

    // ---- one-time: recurrent weights into registers ----
    float w3r[16][3];
    #pragma unroll
    for (int r = 0; r < 3; ++r) {
        const int rho = rg * 3 + r;
        const int g = rho >> 4, jloc = rho & 15;
        const float* wsrc = (g == 0) ? Whi : ((g == 1) ? Whc : Who);
        const float* wp = wsrc + (size_t)(m * 16 + jloc) * 512 + ks;
        #pragma unroll
        for (int i = 0; i < 16; ++i) w3r[i][r] = wp[32 * i];
    }
    if (tid < 48) {
        const int g = tid >> 4, jloc = tid & 15;
        const float* bb = (g == 0) ? bi : ((g == 1) ? bc : bo);
        biasL[tid] = bb[m * 16 + jloc];
    }

    // epilogue identity (tid < 128): j-fastest for coalesced global stores
    const int ejl = tid & 15, eb = tid >> 4;
    const int jg  = m * 16 + ejl;              // global j
    const int bg  = gid * 8 + eb;              // global batch
    float creg = 0.f;

    // own slice of h_0 = 0 directly into LDS (staging always skips own k-range)
    if (tid < 128) hlds[jg * HPAD + eb] = 0.f;
    __syncthreads();

    // staging identity: k = tid, b = q (exactly 8 qwords, no tail)
    const bool own_k = ((tid >> 4) == m);      // k in our own j-slice

    for (int t = 0; t < SEQ; ++t) {
        // ---- prefetch this step's xrow terms (independent of h, overlaps staging) ----
        float xr0 = 0.f, xr1 = 0.f, xr2 = 0.f;
        if (tid < 128) {
            const size_t base = ((size_t)t * NROW + jg) * 64 + bg;
            xr0 = xrow[base];
            xr1 = xrow[base + (size_t)512 * 64];
            xr2 = xrow[base + (size_t)1024 * 64];
        }

        // ---- stage h_t: tagged loads, poll-in-place; own k-range comes via LDS ----
        if (!own_k) {
            const unsigned long long* hsrc =
                hbuf + (size_t)(t & 1) * (BATCH * HID) + (size_t)gid * 8 * 512 + tid;
            const unsigned tgt = (unsigned)t;
            unsigned long long hv[8];
            #pragma unroll
            for (int q = 0; q < 8; ++q)
                hv[q] = __hip_atomic_load(hsrc + (size_t)q * 512, __ATOMIC_RELAXED,
                                          __HIP_MEMORY_SCOPE_AGENT);
            unsigned pend = 0xffu;
            while (pend) {
                unsigned np = 0;
                #pragma unroll
                for (int q = 0; q < 8; ++q) {
                    if ((pend >> q) & 1) {
                        if ((unsigned)(hv[q] >> 32) >= tgt) {
                            hlds[tid * HPAD + q] =
                                __builtin_bit_cast(float, (unsigned)hv[q]);
                        } else np |= 1u << q;
                    }
                }
                if (np) {
                    // reload FIRST (loads in flight), sleep to cover the latency
                    #pragma unroll
                    for (int q = 0; q < 8; ++q)
                        if ((np >> q) & 1)
                            hv[q] = __hip_atomic_load(hsrc + (size_t)q * 512,
                                                      __ATOMIC_RELAXED,
                                                      __HIP_MEMORY_SCOPE_AGENT);
                    __builtin_amdgcn_s_sleep(1);
                }
                pend = np;
            }
        }
        __syncthreads();

        // ---- GEMM: acc[r][b] = sum_k w3r[i][r] * h[k][b], k = ks+32i ----
        float acc[3][8];
        #pragma unroll
        for (int r = 0; r < 3; ++r)
            #pragma unroll
            for (int b = 0; b < 8; ++b) acc[r][b] = 0.f;

        {
            const float* hb = hlds + ks * HPAD;
            #pragma unroll
            for (int i = 0; i < 16; ++i) {
                float hv2[8];
                *(float2*)&hv2[0] = *(const float2*)(hb + i * (32 * HPAD) + 0);
                *(float2*)&hv2[2] = *(const float2*)(hb + i * (32 * HPAD) + 2);
                *(float2*)&hv2[4] = *(const float2*)(hb + i * (32 * HPAD) + 4);
                *(float2*)&hv2[6] = *(const float2*)(hb + i * (32 * HPAD) + 6);
                #pragma unroll
                for (int r = 0; r < 3; ++r)
                    #pragma unroll
                    for (int b = 0; b < 8; ++b)
                        acc[r][b] += w3r[i][r] * hv2[b];
            }
            // ---- reduce over ks on the VALU pipe ----
            #pragma unroll
            for (int r = 0; r < 3; ++r)
                #pragma unroll
                for (int b = 0; b < 8; ++b) {
                    float v = acc[r][b];
                    v = dpp_add<0x121>(v);  // row_ror:1
                    v = dpp_add<0x122>(v);  // row_ror:2
                    v = dpp_add<0x124>(v);  // row_ror:4
                    v = dpp_add<0x128>(v);  // row_ror:8
                    v = dpp_add<0x142>(v);  // row_bcast15 -> lanes 16..31/48..63
                    acc[r][b] = v;
                }
            if (lane == 16 || lane == 48) {
                #pragma unroll
                for (int r = 0; r < 3; ++r) {
                    float* gp = gbuf + (rg * 3 + r) * 8;
                    *(float4*)gp       = make_float4(acc[r][0], acc[r][1], acc[r][2], acc[r][3]);
                    *(float4*)(gp + 4) = make_float4(acc[r][4], acc[r][5], acc[r][6], acc[r][7]);
                }
            }
        }
        __syncthreads();

        // ---- elementwise update (tid < 128): thread = (eb, ejl); publish tagged h ----
        if (tid < 128) {
            const float pi = xr0 + biasL[ejl]      + gbuf[(0 * 16 + ejl) * 8 + eb];
            const float pc = xr1 + biasL[16 + ejl] + gbuf[(1 * 16 + ejl) * 8 + eb];
            const float po = xr2 + biasL[32 + ejl] + gbuf[(2 * 16 + ejl) * 8 + eb];
            const float it = sigf(pi);
            const float ch = tanh_fast(pc);
            const float ot = sigf(po);
            creg = (1.f - it) * creg + it * ch;       // coupled forget gate
            const float hn = ot * tanh_fast(creg);
            const unsigned long long pv =
                ((unsigned long long)(unsigned)(t + 1) << 32) |
                (unsigned long long)__builtin_bit_cast(unsigned, hn);
            // publish first: it is the cross-wg critical path
            __hip_atomic_store(hbuf + (size_t)((t + 1) & 1) * (BATCH * HID)
                                    + (size_t)bg * 512 + jg,
                               pv, __ATOMIC_RELAXED, __HIP_MEMORY_SCOPE_AGENT);
            hlds[jg * HPAD + eb] = hn;                // self-bypass for next step
            out[((size_t)t * 64 + bg) * 512 + jg] = hn;
            if (t == SEQ - 1) {
                out[SBH + (size_t)bg * 512 + jg] = hn;             // h_T
                out[SBH + 32768 + (size_t)bg * 512 + jg] = creg;   // c_T
            }
        }
        // no drain, no flag, no trailing barrier: next iteration's staging only
        // touches hlds entries outside every concurrent reader's range, and the
        // tagged store IS the publication.
    }
}

extern "C" void kernel_launch(void* const* d_in, const int* in_sizes, int n_in,
                              void* d_out, int out_size, void* d_ws, size_t ws_size,
                              hipStream_t stream)
{
    const float* x   = (const float*)d_in[0];
    const float* Wxi = (const float*)d_in[1];
    const float* Whi = (const float*)d_in[2];
    const float* bi  = (const float*)d_in[3];
    const float* Wxc = (const float*)d_in[4];
    const float* Whc = (const float*)d_in[5];
    const float* bc  = (const float*)d_in[6];
    const float* Wxo = (const float*)d_in[7];
    const float* Who = (const float*)d_in[8];
    const float* bo  = (const float*)d_in[9];
    float* out = (float*)d_out;
    char* ws = (char*)d_ws;

    float*              xrow = (float*)ws;
    unsigned long long* hbuf = (unsigned long long*)(ws + XROW_FLOATS * 4);

    // zero tagged h double-buffer: (tag=0, h=0.0f) == h_0, every call
    (void)hipMemsetAsync(hbuf, 0, (size_t)HBUF_QWORDS * 8, stream);

    // xproj: no LDS at all
    hipLaunchKernelGGL(xproj_kernel, dim3(512), dim3(256), 0, stream,
                       x, Wxi, Wxc, Wxo, xrow);
    // scan LDS: h 5120 + gbuf 384 + bias 48 = 5552 floats = 22208 B
    hipLaunchKernelGGL(scan_kernel, dim3(256), dim3(512), 22208, stream,
                       xrow, Whi, Whc, Who, bi, bc, bo, hbuf, out);
}